// Round 9
// baseline (283.452 us; speedup 1.0000x reference)
//
#include <hip/hip_runtime.h>
#include <hip/hip_cooperative_groups.h>
#include <math.h>

// ---------------- constants ----------------
#define KDIM    65536
#define NNODES  100
#define OUTC    60
#define YW      64          // padded col width of Y
#define YSLAB   (NNODES*YW) // 6400 floats per hk

// GEMM chunking: 16 stages of BK=64 -> 1024 k per block, grid 384
#define BK      64
#define ITERS   16
#define SLAB    (BK*ITERS)      // 1024
// f32 fallback GEMM chunking
#define CHUNK   256
#define NKC     256
#define STEPS   (CHUNK/32)

// ws layout (float offsets)
#define WS_Y    10048       // 6*6400 = 38400 floats
#define WS_E    48448       // end of zero region
// bf16 x scratch (byte offsets)
#define XB_OFF_BYTES   245760ull
#define XB_BYTES       (100ull*65536ull*2ull)         // 13107200
// tiled bf16 W: wt[hk][p][c][j], p=k>>3, j=k&7; 8192*60*8 ushorts per hk
#define WT_OFF_BYTES   (XB_OFF_BYTES + XB_BYTES)      // 13352960 (16B aligned)
#define WT_HK_USH      (8192ull*60ull*8ull)           // 3932160 ushorts
#define WT_BYTES       (6ull*WT_HK_USH*2ull)          // 47185920
#define WS_NEED_BYTES  (WT_OFF_BYTES + WT_BYTES)      // 60538880

typedef short bf16x8 __attribute__((ext_vector_type(8)));
typedef float f32x4  __attribute__((ext_vector_type(4)));
typedef unsigned short ushort8 __attribute__((ext_vector_type(8)));

__device__ inline unsigned short f2bf(float f) {
    union { float f; unsigned u; } x; x.f = f;
    unsigned r = x.u + 0x7FFFu + ((x.u >> 16) & 1u);   // RNE (finite inputs)
    return (unsigned short)(r >> 16);
}

// ---- prep: x f32->bf16, W f32->tiled bf16 (wt[p][c][j]=W[p*8+j][c]), zero Y/out
// grid 1536 = 6 hk x 256 k-slabs of 256 k. Per block: read [256k][60c] f32 tile
// coalesced (3840 float4), LDS-transpose, write 1920 ushort8 coalesced.
// All blocks also grid-stride the x conversion.
__global__ __launch_bounds__(256) void k_prep(const float* __restrict__ x,
                                              const float* __restrict__ wa,
                                              const float* __restrict__ wc,
                                              ushort8* __restrict__ xb,
                                              unsigned short* __restrict__ wt,
                                              float* __restrict__ Y,
                                              float* __restrict__ out) {
    __shared__ float tile[15360];                 // 61440 B
    const int t  = threadIdx.x;
    const int g  = blockIdx.x * 256 + t;
    // zero Y + out
    if (g < 9600) ((f32x4*)Y)[g] = (f32x4){};
    if (g < 101)  out[g] = 0.f;
    // x convert: 819200 ushort8 units over 393216 threads
    for (int i = g; i < 819200; i += 393216) {
        const float4 lo = ((const float4*)x)[2 * i];
        const float4 hi = ((const float4*)x)[2 * i + 1];
        ushort8 o;
        o[0] = f2bf(lo.x); o[1] = f2bf(lo.y); o[2] = f2bf(lo.z); o[3] = f2bf(lo.w);
        o[4] = f2bf(hi.x); o[5] = f2bf(hi.y); o[6] = f2bf(hi.z); o[7] = f2bf(hi.w);
        xb[i] = o;
    }
    // W tile convert
    const int hk   = blockIdx.x >> 8;             // 0..5
    const int ws_  = blockIdx.x & 255;            // k-slab
    const int kb   = ws_ * 256;
    const float* Wg = (hk < 3 ? wa : wc) + (size_t)(hk % 3) * ((size_t)KDIM * OUTC);
    const float4* src4 = (const float4*)(Wg + (size_t)kb * OUTC);
#pragma unroll
    for (int i = 0; i < 15; ++i)
        ((float4*)tile)[t + i * 256] = src4[t + i * 256];
    __syncthreads();
    ushort8* dst = (ushort8*)(wt + (size_t)hk * WT_HK_USH) + (size_t)(ws_ * 32) * 60;
#pragma unroll
    for (int i = 0; i < 8; ++i) {
        int idx2 = t + i * 256;
        if (idx2 < 1920) {
            int pp = idx2 / 60, c = idx2 - pp * 60;
            ushort8 o;
#pragma unroll
            for (int j = 0; j < 8; ++j) o[j] = f2bf(tile[(pp * 8 + j) * 60 + c]);
            dst[idx2] = o;
        }
    }
}

// ---- main (cooperative): GEMM all 384 blocks -> grid.sync -> emb+heads -------
// GEMM: 6 hk x 64 kc, block 256 = 4 waves (ng), 7 m-tiles/wave, 16 stages BK=64,
// 3-deep pipeline. Per stage per wave: 4 A global_load_lds + 2 B bf16x8 loads
// from tiled wt (ONE 16B contiguous load per lane per s-step; 4x256B segments
// per instruction) = 6 loads -> vmcnt(12) = stages t+1,t+2 in flight.
// No f2bf in the loop; W bytes halved.
union SMem {
    struct { unsigned short Ab[3][14 * 512]; unsigned short pad[512]; } g; // 44032 B
    struct { float Sp[NNODES * 101]; float y0[NNODES], y1[NNODES], y2[NNODES],
             t2[NNODES], e[NNODES]; int deg[NNODES]; float dinv[NNODES];
             float wsum[4]; } h;                                           // 43216 B
};

__global__ __launch_bounds__(256) void k_main(const unsigned short* __restrict__ xb,
                                              const unsigned short* __restrict__ wt,
                                              float* __restrict__ Y,
                                              const int* __restrict__ ei,
                                              const float* __restrict__ vnr,
                                              const float* __restrict__ avw,
                                              const float* __restrict__ avb,
                                              const float* __restrict__ cvw,
                                              const float* __restrict__ cvb,
                                              const float* __restrict__ acb,
                                              const float* __restrict__ ccb,
                                              const float* __restrict__ afcb,
                                              const float* __restrict__ cfcb,
                                              const float* __restrict__ afw,
                                              const float* __restrict__ cfw,
                                              float* __restrict__ out) {
    __shared__ SMem sm;
    {   // ---------------- GEMM phase ----------------
        const int b    = blockIdx.x;
        const int lo8  = b & 7, q = b >> 3;      // q: 0..47
        const int hk   = q % 6;
        const int kc   = lo8 + 8 * (q / 6);      // 0..63; same-kc 6 blocks share XCD
        const int wave = threadIdx.x >> 6;
        const int lane = threadIdx.x & 63;
        const int n16  = lane & 15;
        const int quad = lane >> 4;
        const int c0   = wave * 16;
        const int cidx = min(c0 + n16, OUTC - 1);
        const int kb0  = kc * SLAB;

        const unsigned short* wth = wt + (size_t)hk * WT_HK_USH;

        auto DMA = [&](int buf, int kb) {
#pragma unroll
            for (int j5 = 0; j5 < 4; ++j5) {
                int j = wave + j5 * 4;
                int chunk = j * 64 + lane;
                int m  = chunk >> 3;
                int cc = (chunk & 7) ^ (m & 7);
                const unsigned short* src =
                    xb + (size_t)min(m, NNODES - 1) * KDIM + kb + cc * 8;
                void* dst = (j < 14) ? (void*)&sm.g.Ab[buf][j * 512] : (void*)sm.g.pad;
                __builtin_amdgcn_global_load_lds(
                    (const __attribute__((address_space(1))) void*)src,
                    (__attribute__((address_space(3))) void*)dst, 16, 0, 0);
            }
        };
        bf16x8 breg[3][2];
        auto LOADB = [&](int pb, int kb) {
            const int pbase = kb >> 3;
#pragma unroll
            for (int s = 0; s < 2; ++s) {
                size_t idx = (size_t)(pbase + s * 4 + quad) * 60 + cidx;
                breg[pb][s] = *(const bf16x8*)(wth + idx * 8);
            }
        };

        DMA(0, kb0);           LOADB(0, kb0);
        DMA(1, kb0 + BK);      LOADB(1, kb0 + BK);
        f32x4 acc[7] = {};

#pragma unroll
        for (int it = 0; it < ITERS; ++it) {
            if (it + 2 < ITERS) {
                DMA((it + 2) % 3, kb0 + (it + 2) * BK);
                LOADB((it + 2) % 3, kb0 + (it + 2) * BK);
                asm volatile("s_waitcnt vmcnt(12)" ::: "memory"); // stage t landed
            } else if (it + 2 == ITERS) {
                asm volatile("s_waitcnt vmcnt(6)" ::: "memory");
            } else {
                asm volatile("s_waitcnt vmcnt(0)" ::: "memory");
            }
            __builtin_amdgcn_s_barrier();
            const unsigned short* A = sm.g.Ab[it % 3];
#pragma unroll
            for (int s = 0; s < 2; ++s) {
                bf16x8 bfr = breg[it % 3][s];
                int ch = (s * 4 + quad) ^ (n16 & 7);
#pragma unroll
                for (int t = 0; t < 7; ++t) {
                    bf16x8 afr = *(const bf16x8*)(A + (t * 16 + n16) * BK + ch * 8);
                    acc[t] = __builtin_amdgcn_mfma_f32_16x16x32_bf16(afr, bfr, acc[t], 0, 0, 0);
                }
            }
            __builtin_amdgcn_s_barrier();
        }

        float* Yb = Y + hk * YSLAB;
#pragma unroll
        for (int t = 0; t < 7; ++t)
#pragma unroll
            for (int r = 0; r < 4; ++r) {
                int row = t * 16 + quad * 4 + r;
                if (row < NNODES)
                    atomicAdd(&Yb[row * YW + c0 + n16], acc[t][r]);
            }
    }

    cooperative_groups::this_grid().sync();

    // ---------------- emb + heads phase (blocks 0..119) ----------------
    const int b = blockIdx.x;
    if (b >= 120) return;
    const int head = b / OUTC, c = b % OUTC;
    const int t = threadIdx.x;
    const int* src = ei;
    const int* dst = ei + 1600;

    for (int i = t; i < NNODES * 101; i += 256) sm.h.Sp[i] = 0.f;
    if (t < NNODES) sm.h.deg[t] = 0;
    __syncthreads();
    for (int ed = t; ed < 1600; ed += 256) atomicAdd(&sm.h.deg[src[ed]], 1);
    __syncthreads();
    if (t < NNODES) { int d = sm.h.deg[t]; sm.h.dinv[t] = (d > 0) ? rsqrtf((float)d) : 0.f; }
    __syncthreads();
    for (int ed = t; ed < 1600; ed += 256) {
        int s = src[ed], d = dst[ed];
        atomicAdd(&sm.h.Sp[d * 101 + s], -sm.h.dinv[s] * sm.h.dinv[d]);
    }
    float* Yh = Y + (size_t)head * 3 * YSLAB;
    if (t < NNODES) {   // atomic reads: device-scope coherent across XCDs
        sm.h.y0[t] = atomicAdd(&Yh[t * YW + c], 0.f);
        sm.h.y1[t] = atomicAdd(&Yh[YSLAB + t * YW + c], 0.f);
        sm.h.y2[t] = atomicAdd(&Yh[2 * YSLAB + t * YW + c], 0.f);
    }
    __syncthreads();

    float z1 = 0.f, s2 = 0.f;
    if (t < NNODES) {
        const float* sr = sm.h.Sp + t * 101;
        for (int m = 0; m < NNODES; ++m) { z1 += sr[m] * sm.h.y1[m]; s2 += sr[m] * sm.h.y2[m]; }
        sm.h.t2[t] = s2;
    }
    __syncthreads();
    float ev = 0.f;
    if (t < NNODES) {
        const float* sr = sm.h.Sp + t * 101;
        float t3 = 0.f;
        for (int m = 0; m < NNODES; ++m) t3 += sr[m] * sm.h.t2[m];
        const float* cb = head ? ccb : acb;
        const float* vw = head ? cvw : avw;
        const float* vb = head ? cvb : avb;
        float u  = sm.h.y0[t] + z1 + 2.f * t3 - sm.h.y2[t] + cb[c];
        float vs = vnr[0] * vw[c]        + vb[c]
                 + vnr[1] * vw[OUTC + c] + vb[OUTC + c]
                 + vnr[2] * vw[2*OUTC+c] + vb[2*OUTC+c];
        ev = tanhf(u) + vs;
        sm.h.e[t] = ev;
    }
    __syncthreads();

    if (head == 0) {
        if (t < NNODES) {
            float s = (c == 0) ? afcb[t] : 0.f;
            const float* wrow = afw + (size_t)c * 100 + t;
#pragma unroll 4
            for (int n = 0; n < NNODES; ++n) s += sm.h.e[n] * wrow[(size_t)n * 6000];
            atomicAdd(&out[t], s);
        }
    } else {
        float p = (t < NNODES) ? ev * cfw[t * OUTC + c] : 0.f;
#pragma unroll
        for (int off = 32; off > 0; off >>= 1) p += __shfl_down(p, off, 64);
        if ((t & 63) == 0) sm.h.wsum[t >> 6] = p;
        __syncthreads();
        if (t == 0) atomicAdd(&out[100],
            sm.h.wsum[0] + sm.h.wsum[1] + sm.h.wsum[2] + sm.h.wsum[3] +
            (c == 0 ? cfcb[0] : 0.f));
    }
}

// ---- non-cooperative split of k_main (fallback if coop launch rejected) ------
__global__ __launch_bounds__(256) void k_gemm_nc(const unsigned short* __restrict__ xb,
                                                 const unsigned short* __restrict__ wt,
                                                 float* __restrict__ Y) {
    __shared__ SMem sm;
    const int b    = blockIdx.x;
    const int lo8  = b & 7, q = b >> 3;
    const int hk   = q % 6;
    const int kc   = lo8 + 8 * (q / 6);
    const int wave = threadIdx.x >> 6;
    const int lane = threadIdx.x & 63;
    const int n16  = lane & 15;
    const int quad = lane >> 4;
    const int c0   = wave * 16;
    const int cidx = min(c0 + n16, OUTC - 1);
    const int kb0  = kc * SLAB;
    const unsigned short* wth = wt + (size_t)hk * WT_HK_USH;

    auto DMA = [&](int buf, int kb) {
#pragma unroll
        for (int j5 = 0; j5 < 4; ++j5) {
            int j = wave + j5 * 4;
            int chunk = j * 64 + lane;
            int m  = chunk >> 3;
            int cc = (chunk & 7) ^ (m & 7);
            const unsigned short* src =
                xb + (size_t)min(m, NNODES - 1) * KDIM + kb + cc * 8;
            void* dst = (j < 14) ? (void*)&sm.g.Ab[buf][j * 512] : (void*)sm.g.pad;
            __builtin_amdgcn_global_load_lds(
                (const __attribute__((address_space(1))) void*)src,
                (__attribute__((address_space(3))) void*)dst, 16, 0, 0);
        }
    };
    bf16x8 breg[3][2];
    auto LOADB = [&](int pb, int kb) {
        const int pbase = kb >> 3;
#pragma unroll
        for (int s = 0; s < 2; ++s) {
            size_t idx = (size_t)(pbase + s * 4 + quad) * 60 + cidx;
            breg[pb][s] = *(const bf16x8*)(wth + idx * 8);
        }
    };

    DMA(0, kb0);           LOADB(0, kb0);
    DMA(1, kb0 + BK);      LOADB(1, kb0 + BK);
    f32x4 acc[7] = {};

#pragma unroll
    for (int it = 0; it < ITERS; ++it) {
        if (it + 2 < ITERS) {
            DMA((it + 2) % 3, kb0 + (it + 2) * BK);
            LOADB((it + 2) % 3, kb0 + (it + 2) * BK);
            asm volatile("s_waitcnt vmcnt(12)" ::: "memory");
        } else if (it + 2 == ITERS) {
            asm volatile("s_waitcnt vmcnt(6)" ::: "memory");
        } else {
            asm volatile("s_waitcnt vmcnt(0)" ::: "memory");
        }
        __builtin_amdgcn_s_barrier();
        const unsigned short* A = sm.g.Ab[it % 3];
#pragma unroll
        for (int s = 0; s < 2; ++s) {
            bf16x8 bfr = breg[it % 3][s];
            int ch = (s * 4 + quad) ^ (n16 & 7);
#pragma unroll
            for (int t = 0; t < 7; ++t) {
                bf16x8 afr = *(const bf16x8*)(A + (t * 16 + n16) * BK + ch * 8);
                acc[t] = __builtin_amdgcn_mfma_f32_16x16x32_bf16(afr, bfr, acc[t], 0, 0, 0);
            }
        }
        __builtin_amdgcn_s_barrier();
    }

    float* Yb = Y + hk * YSLAB;
#pragma unroll
    for (int t = 0; t < 7; ++t)
#pragma unroll
        for (int r = 0; r < 4; ++r) {
            int row = t * 16 + quad * 4 + r;
            if (row < NNODES)
                atomicAdd(&Yb[row * YW + c0 + n16], acc[t][r]);
        }
}

__global__ __launch_bounds__(128) void k_embh_fb(const int* __restrict__ ei,
                                                 const float* __restrict__ Y,
                                                 const float* __restrict__ vnr,
                                                 const float* __restrict__ avw,
                                                 const float* __restrict__ avb,
                                                 const float* __restrict__ cvw,
                                                 const float* __restrict__ cvb,
                                                 const float* __restrict__ acb,
                                                 const float* __restrict__ ccb,
                                                 const float* __restrict__ afcb,
                                                 const float* __restrict__ cfcb,
                                                 const float* __restrict__ afw,
                                                 const float* __restrict__ cfw,
                                                 float* __restrict__ out) {
    __shared__ float Sp[NNODES * 101];
    __shared__ float y0[NNODES], y1[NNODES], y2[NNODES], t2[NNODES], e[NNODES];
    __shared__ int   deg[NNODES];
    __shared__ float dinv[NNODES];
    const int b = blockIdx.x, head = b / OUTC, c = b % OUTC;
    const int t = threadIdx.x;
    const int* src = ei;
    const int* dst = ei + 1600;
    for (int i = t; i < NNODES * 101; i += 128) Sp[i] = 0.f;
    if (t < NNODES) deg[t] = 0;
    __syncthreads();
    for (int ed = t; ed < 1600; ed += 128) atomicAdd(&deg[src[ed]], 1);
    __syncthreads();
    if (t < NNODES) { int d = deg[t]; dinv[t] = (d > 0) ? rsqrtf((float)d) : 0.f; }
    __syncthreads();
    for (int ed = t; ed < 1600; ed += 128) {
        int s = src[ed], d = dst[ed];
        atomicAdd(&Sp[d * 101 + s], -dinv[s] * dinv[d]);
    }
    const float* Yh = Y + (size_t)head * 3 * YSLAB;
    if (t < NNODES) {
        y0[t] = Yh[t * YW + c];
        y1[t] = Yh[YSLAB + t * YW + c];
        y2[t] = Yh[2 * YSLAB + t * YW + c];
    }
    __syncthreads();
    float z1 = 0.f, s2 = 0.f;
    if (t < NNODES) {
        const float* sr = Sp + t * 101;
        for (int m = 0; m < NNODES; ++m) { z1 += sr[m] * y1[m]; s2 += sr[m] * y2[m]; }
        t2[t] = s2;
    }
    __syncthreads();
    float ev = 0.f;
    if (t < NNODES) {
        const float* sr = Sp + t * 101;
        float t3 = 0.f;
        for (int m = 0; m < NNODES; ++m) t3 += sr[m] * t2[m];
        const float* cb = head ? ccb : acb;
        const float* vw = head ? cvw : avw;
        const float* vb = head ? cvb : avb;
        float u  = y0[t] + z1 + 2.f * t3 - y2[t] + cb[c];
        float vs = vnr[0] * vw[c]        + vb[c]
                 + vnr[1] * vw[OUTC + c] + vb[OUTC + c]
                 + vnr[2] * vw[2*OUTC+c] + vb[2*OUTC+c];
        ev = tanhf(u) + vs;
        e[t] = ev;
    }
    __syncthreads();
    if (head == 0) {
        if (t < NNODES) {
            float s = (c == 0) ? afcb[t] : 0.f;
            const float* wrow = afw + (size_t)c * 100 + t;
#pragma unroll 4
            for (int n = 0; n < NNODES; ++n) s += e[n] * wrow[(size_t)n * 6000];
            atomicAdd(&out[t], s);
        }
    } else {
        float p = (t < NNODES) ? ev * cfw[t * OUTC + c] : 0.f;
#pragma unroll
        for (int off = 32; off > 0; off >>= 1) p += __shfl_down(p, off, 64);
        __shared__ float wsum[2];
        if ((t & 63) == 0) wsum[t >> 6] = p;
        __syncthreads();
        if (t == 0) atomicAdd(&out[100], wsum[0] + wsum[1] + (c == 0 ? cfcb[0] : 0.f));
    }
}

// ---------------- fallback f32 GEMM (used only if ws is too small) -------------
__global__ __launch_bounds__(256, 2) void k_gemm_f32(const float* __restrict__ x,
                                                     const float* __restrict__ wa,
                                                     const float* __restrict__ wc,
                                                     float* __restrict__ Y) {
    const int hk   = blockIdx.x;
    const int kc   = blockIdx.y;
    const int wave = threadIdx.x >> 6;
    const int lane = threadIdx.x & 63;
    const int n16  = lane & 15;
    const int quad = lane >> 4;
    const float* W = (hk < 3 ? wa : wc) + (size_t)(hk % 3) * ((size_t)KDIM * OUTC);
    const int c0   = wave * 16;
    const int cidx = min(c0 + n16, OUTC - 1);
    const int kb0  = kc * CHUNK + quad * 8;
    const float* ap[7];
#pragma unroll
    for (int t = 0; t < 7; ++t)
        ap[t] = x + (size_t)min(n16 + 16 * t, NNODES - 1) * KDIM + kb0;
    const float* bp = W + (size_t)kb0 * OUTC + cidx;
    f32x4 acc[7] = {};
#pragma unroll 2
    for (int s = 0; s < STEPS; ++s) {
        bf16x8 bfr;
        const float* qq = bp + (size_t)s * 32 * OUTC;
#pragma unroll
        for (int j = 0; j < 8; ++j) bfr[j] = (short)f2bf(qq[j * OUTC]);
#pragma unroll
        for (int t = 0; t < 7; ++t) {
            const float* p = ap[t] + s * 32;
            float4 lo = *(const float4*)p;
            float4 hi = *(const float4*)(p + 4);
            bf16x8 afr;
            afr[0] = (short)f2bf(lo.x); afr[1] = (short)f2bf(lo.y);
            afr[2] = (short)f2bf(lo.z); afr[3] = (short)f2bf(lo.w);
            afr[4] = (short)f2bf(hi.x); afr[5] = (short)f2bf(hi.y);
            afr[6] = (short)f2bf(hi.z); afr[7] = (short)f2bf(hi.w);
            acc[t] = __builtin_amdgcn_mfma_f32_16x16x32_bf16(afr, bfr, acc[t], 0, 0, 0);
        }
    }
    float* Yb = Y + hk * YSLAB;
#pragma unroll
    for (int t = 0; t < 7; ++t)
#pragma unroll
        for (int r = 0; r < 4; ++r) {
            int row = t * 16 + quad * 4 + r;
            if (row < NNODES)
                atomicAdd(&Yb[row * YW + c0 + n16], acc[t][r]);
        }
}

// ---------------- launch ----------------
extern "C" void kernel_launch(void* const* d_in, const int* in_sizes, int n_in,
                              void* d_out, int out_size, void* d_ws, size_t ws_size,
                              hipStream_t stream) {
    const float* x    = (const float*)d_in[0];
    const int*   ei   = (const int*)  d_in[1];
    const float* vnr  = (const float*)d_in[2];
    const float* wa   = (const float*)d_in[3];
    const float* acb  = (const float*)d_in[4];
    const float* wc   = (const float*)d_in[5];
    const float* ccb  = (const float*)d_in[6];
    const float* avw  = (const float*)d_in[7];
    const float* avb  = (const float*)d_in[8];
    const float* cvw  = (const float*)d_in[9];
    const float* cvb  = (const float*)d_in[10];
    const float* afw  = (const float*)d_in[11];
    const float* afcb = (const float*)d_in[12];
    const float* cfw  = (const float*)d_in[13];
    const float* cfcb = (const float*)d_in[14];

    float* ws = (float*)d_ws;
    float* Y  = ws + WS_Y;
    float* out = (float*)d_out;

    if (ws_size >= WS_NEED_BYTES) {
        unsigned short* xb = (unsigned short*)((char*)d_ws + XB_OFF_BYTES);
        unsigned short* wt = (unsigned short*)((char*)d_ws + WT_OFF_BYTES);
        k_prep<<<1536, 256, 0, stream>>>(x, wa, wc, (ushort8*)xb, wt, Y, out);
        void* args[] = { (void*)&xb, (void*)&wt, (void*)&Y, (void*)&ei,
                         (void*)&vnr, (void*)&avw, (void*)&avb, (void*)&cvw,
                         (void*)&cvb, (void*)&acb, (void*)&ccb, (void*)&afcb,
                         (void*)&cfcb, (void*)&afw, (void*)&cfw, (void*)&out };
        hipError_t e = hipLaunchCooperativeKernel((const void*)k_main, dim3(384),
                                                  dim3(256), args, 0, stream);
        if (e != hipSuccess) {   // coop launch rejected -> non-coop split
            k_gemm_nc<<<384, 256, 0, stream>>>(xb, wt, Y);
            k_embh_fb<<<120, 128, 0, stream>>>(ei, Y, vnr, avw, avb, cvw, cvb,
                                               acb, ccb, afcb, cfcb, afw, cfw, out);
        }
    } else {
        hipMemsetAsync((char*)d_ws + WS_Y * 4, 0, (WS_E - WS_Y) * 4, stream);
        hipMemsetAsync(d_out, 0, 101 * sizeof(float), stream);
        k_gemm_f32<<<dim3(6, NKC), 256, 0, stream>>>(x, wa, wc, Y);
        k_embh_fb<<<120, 128, 0, stream>>>(ei, Y, vnr, avw, avb, cvw, cvb,
                                           acb, ccb, afcb, cfcb, afw, cfw, out);
    }
}

// Round 10
// 207.417 us; speedup vs baseline: 1.3666x; 1.3666x over previous
//
#include <hip/hip_runtime.h>
#include <math.h>

// ---------------- constants ----------------
#define KDIM    65536
#define NNODES  100
#define OUTC    60
#define YW      64          // padded col width of Y
#define YSLAB   (NNODES*YW) // 6400 floats per hk

// GEMM: 16 stages of BK=64 -> 1024 k per block, grid 384 (all co-resident, 2/CU)
#define BK      64
#define ITERS   16
#define SLAB    (BK*ITERS)      // 1024
// f32 fallback GEMM chunking
#define CHUNK   256
#define NKC     256
#define STEPS   (CHUNK/32)

// ws layout (float offsets)
#define WS_Y    10048       // 6*6400 = 38400 floats
#define WS_E    48448       // end of zero region
// bf16 x scratch (byte offsets)
#define XB_OFF_BYTES   245760ull
#define XB_BYTES       (100ull*65536ull*2ull)         // 13107200
#define WS_NEED_BYTES  (XB_OFF_BYTES + XB_BYTES)      // 13352960

typedef short bf16x8 __attribute__((ext_vector_type(8)));
typedef float f32x4  __attribute__((ext_vector_type(4)));
typedef unsigned short ushort8 __attribute__((ext_vector_type(8)));

__device__ inline unsigned short f2bf(float f) {
    union { float f; unsigned u; } x; x.f = f;
    unsigned r = x.u + 0x7FFFu + ((x.u >> 16) & 1u);   // RNE (finite inputs)
    return (unsigned short)(r >> 16);
}

// -- pass 1: x f32 -> bf16 stream; also zero Y accumulators and out -------------
__global__ __launch_bounds__(256) void k_cvt_x(const float* __restrict__ x,
                                               ushort8* __restrict__ xb,
                                               float* __restrict__ Y,
                                               float* __restrict__ out) {
    int g = blockIdx.x * 256 + threadIdx.x;
    if (g < 9600) ((f32x4*)Y)[g] = (f32x4){};   // zero 6*6400 floats for atomics
    if (g < 101)  out[g] = 0.f;                 // logits+value accumulate atomically
    for (int i = g; i < 819200; i += 204800) {
        const float4 lo = ((const float4*)x)[2 * i];
        const float4 hi = ((const float4*)x)[2 * i + 1];
        ushort8 o;
        o[0] = f2bf(lo.x); o[1] = f2bf(lo.y); o[2] = f2bf(lo.z); o[3] = f2bf(lo.w);
        o[4] = f2bf(hi.x); o[5] = f2bf(hi.y); o[6] = f2bf(hi.z); o[7] = f2bf(hi.w);
        xb[i] = o;
    }
}

// ---- pass 2: GEMM — BOTH operands via contiguous global_load_lds DMA,
//      2-deep counted-vmcnt pipeline (the untested combination).
// Grid 384 = 6 hk x 64 kc (XCD-swizzled), block 256 = 4 waves (ng), 7 m-tiles.
// Per stage per block: 32 DMA instrs (A 14 + W 15 + 3 pad), exactly 8 per wave
// -> s_waitcnt vmcnt(8) after issuing stage t+1 keeps its 8 loads in flight
// across both barriers while stage t computes. W instrs are FULLY contiguous
// 1KB (vs round-3/6's 240B-stride dword gathers whose per-segment coalescer
// cost ~ matched the 41us wall). B-frags: LDS f32 read + f2bf (VALU, hidden).
// LDS 60.4 KB -> 2 blocks/CU; 384 blocks all co-resident.
__global__ __launch_bounds__(256) void k_gemm11(const unsigned short* __restrict__ xb,
                                                const float* __restrict__ wa,
                                                const float* __restrict__ wc,
                                                float* __restrict__ Y) {
    __shared__ unsigned short Ab[2][14 * 512];   // 2 x 14336 B
    __shared__ float          Wf[2][15 * 256];   // 2 x 15360 B (64k x 60c f32)
    __shared__ float          padlds[256];       // 1 KB dummy DMA target
    const int b    = blockIdx.x;
    const int lo8  = b & 7, q = b >> 3;          // q: 0..47
    const int hk   = q % 6;
    const int kc   = lo8 + 8 * (q / 6);          // 0..63; same-kc blocks share XCD
    const int wave = threadIdx.x >> 6;
    const int lane = threadIdx.x & 63;
    const int n16  = lane & 15;
    const int quad = lane >> 4;
    const int c0   = wave * 16;
    const int cidx = min(c0 + n16, OUTC - 1);    // cols 60..63 junk -> Y pad cols
    const int kb0  = kc * SLAB;

    const float* Wg = (hk < 3 ? wa : wc) + (size_t)(hk % 3) * ((size_t)KDIM * OUTC);

    auto DMA = [&](int buf, int kb) {
#pragma unroll
        for (int j5 = 0; j5 < 8; ++j5) {
            int j = wave + j5 * 4;               // 8 slots per wave, 32 total
            const void* src; void* dst;
            if (j < 14) {                        // A: swizzled bf16 rows
                int chunk = j * 64 + lane;
                int m  = chunk >> 3;
                int cc = (chunk & 7) ^ (m & 7);
                src = xb + (size_t)min(m, NNODES - 1) * KDIM + kb + cc * 8;
                dst = &Ab[buf][j * 512];
            } else if (j < 29) {                 // W: contiguous f32 [64][60]
                int wj = j - 14;
                src = Wg + (size_t)kb * OUTC + wj * 256 + lane * 4;
                dst = &Wf[buf][wj * 256];
            } else {                             // pad: keep counts uniform
                src = xb + lane * 8;
                dst = padlds;
            }
            __builtin_amdgcn_global_load_lds(
                (const __attribute__((address_space(1))) void*)src,
                (__attribute__((address_space(3))) void*)dst, 16, 0, 0);
        }
    };

    DMA(0, kb0);
    f32x4 acc[7] = {};

#pragma unroll
    for (int it = 0; it < ITERS; ++it) {
        if (it + 1 < ITERS) {
            DMA((it + 1) & 1, kb0 + (it + 1) * BK);           // t+1 in flight
            asm volatile("s_waitcnt vmcnt(8)" ::: "memory");  // stage t landed
        } else {
            asm volatile("s_waitcnt vmcnt(0)" ::: "memory");
        }
        __builtin_amdgcn_s_barrier();            // stage t visible to all waves
        const unsigned short* A = Ab[it & 1];
        const float*          B = Wf[it & 1];
#pragma unroll
        for (int s = 0; s < 2; ++s) {
            // B-frag: quad-rotated j order -> 4 disjoint 16-bank windows
            bf16x8 bfr;
#pragma unroll
            for (int jq = 0; jq < 8; ++jq) {
                int jj = (jq + quad * 2) & 7;
                bfr[jj] = (short)f2bf(B[(s * 32 + quad * 8 + jj) * OUTC + cidx]);
            }
            int ch = (s * 4 + quad) ^ (n16 & 7);
#pragma unroll
            for (int t = 0; t < 7; ++t) {
                bf16x8 afr = *(const bf16x8*)(A + (t * 16 + n16) * BK + ch * 8);
                acc[t] = __builtin_amdgcn_mfma_f32_16x16x32_bf16(afr, bfr, acc[t], 0, 0, 0);
            }
        }
        __builtin_amdgcn_s_barrier();            // reads of buf[it&1] done
    }

    // D layout: col = lane&15, row = quad*4 + r within 16x16 tile
    float* Yb = Y + hk * YSLAB;
#pragma unroll
    for (int t = 0; t < 7; ++t)
#pragma unroll
        for (int r = 0; r < 4; ++r) {
            int row = t * 16 + quad * 4 + r;
            if (row < NNODES)
                atomicAdd(&Yb[row * YW + c0 + n16], acc[t][r]);
        }
}

// ---------------- fallback f32 GEMM (used only if ws is too small) -------------
__global__ __launch_bounds__(256, 2) void k_gemm_f32(const float* __restrict__ x,
                                                     const float* __restrict__ wa,
                                                     const float* __restrict__ wc,
                                                     float* __restrict__ Y) {
    const int hk   = blockIdx.x;
    const int kc   = blockIdx.y;
    const int wave = threadIdx.x >> 6;
    const int lane = threadIdx.x & 63;
    const int n16  = lane & 15;
    const int quad = lane >> 4;
    const float* W = (hk < 3 ? wa : wc) + (size_t)(hk % 3) * ((size_t)KDIM * OUTC);
    const int c0   = wave * 16;
    const int cidx = min(c0 + n16, OUTC - 1);
    const int kb0  = kc * CHUNK + quad * 8;
    const float* ap[7];
#pragma unroll
    for (int t = 0; t < 7; ++t)
        ap[t] = x + (size_t)min(n16 + 16 * t, NNODES - 1) * KDIM + kb0;
    const float* bp = W + (size_t)kb0 * OUTC + cidx;
    f32x4 acc[7] = {};
#pragma unroll 2
    for (int s = 0; s < STEPS; ++s) {
        bf16x8 bfr;
        const float* qq = bp + (size_t)s * 32 * OUTC;
#pragma unroll
        for (int j = 0; j < 8; ++j) bfr[j] = (short)f2bf(qq[j * OUTC]);
#pragma unroll
        for (int t = 0; t < 7; ++t) {
            const float* p = ap[t] + s * 32;
            float4 lo = *(const float4*)p;
            float4 hi = *(const float4*)(p + 4);
            bf16x8 afr;
            afr[0] = (short)f2bf(lo.x); afr[1] = (short)f2bf(lo.y);
            afr[2] = (short)f2bf(lo.z); afr[3] = (short)f2bf(lo.w);
            afr[4] = (short)f2bf(hi.x); afr[5] = (short)f2bf(hi.y);
            afr[6] = (short)f2bf(hi.z); afr[7] = (short)f2bf(hi.w);
            acc[t] = __builtin_amdgcn_mfma_f32_16x16x32_bf16(afr, bfr, acc[t], 0, 0, 0);
        }
    }
    float* Yb = Y + hk * YSLAB;
#pragma unroll
    for (int t = 0; t < 7; ++t)
#pragma unroll
        for (int r = 0; r < 4; ++r) {
            int row = t * 16 + quad * 4 + r;
            if (row < NNODES)
                atomicAdd(&Yb[row * YW + c0 + n16], acc[t][r]);
        }
}

// -- kernel 3: build S in LDS + emb = tanh(cheb)+vnr + FUSED head matmuls -------
__global__ __launch_bounds__(128) void k_embh(const int* __restrict__ ei,
                                              const float* __restrict__ Y,
                                              const float* __restrict__ vnr,
                                              const float* __restrict__ avw,
                                              const float* __restrict__ avb,
                                              const float* __restrict__ cvw,
                                              const float* __restrict__ cvb,
                                              const float* __restrict__ acb,
                                              const float* __restrict__ ccb,
                                              const float* __restrict__ afcb,
                                              const float* __restrict__ cfcb,
                                              const float* __restrict__ afw,
                                              const float* __restrict__ cfw,
                                              float* __restrict__ out) {
    __shared__ float Sp[NNODES * 101];
    __shared__ float y0[NNODES], y1[NNODES], y2[NNODES], t2[NNODES];
    __shared__ float e[NNODES];
    __shared__ int   deg[NNODES];
    __shared__ float dinv[NNODES];
    const int b = blockIdx.x, head = b / OUTC, c = b % OUTC;
    const int t = threadIdx.x;
    const int* src = ei;
    const int* dst = ei + 1600;

    for (int i = t; i < NNODES * 101; i += 128) Sp[i] = 0.f;
    if (t < NNODES) deg[t] = 0;
    __syncthreads();
    for (int ed = t; ed < 1600; ed += 128) atomicAdd(&deg[src[ed]], 1);
    __syncthreads();
    if (t < NNODES) { int d = deg[t]; dinv[t] = (d > 0) ? rsqrtf((float)d) : 0.f; }
    __syncthreads();
    for (int ed = t; ed < 1600; ed += 128) {
        int s = src[ed], d = dst[ed];
        atomicAdd(&Sp[d * 101 + s], -dinv[s] * dinv[d]);
    }
    const float* Yh = Y + (size_t)head * 3 * YSLAB;
    if (t < NNODES) {
        y0[t] = Yh[t * YW + c];
        y1[t] = Yh[YSLAB + t * YW + c];
        y2[t] = Yh[2 * YSLAB + t * YW + c];
    }
    __syncthreads();

    float z1 = 0.f, s2 = 0.f;
    if (t < NNODES) {
        const float* sr = Sp + t * 101;
        for (int m = 0; m < NNODES; ++m) { z1 += sr[m] * y1[m]; s2 += sr[m] * y2[m]; }
        t2[t] = s2;
    }
    __syncthreads();
    float ev = 0.f;
    if (t < NNODES) {
        const float* sr = Sp + t * 101;
        float t3 = 0.f;
        for (int m = 0; m < NNODES; ++m) t3 += sr[m] * t2[m];
        const float* cb = head ? ccb : acb;
        const float* vw = head ? cvw : avw;
        const float* vb = head ? cvb : avb;
        float u  = y0[t] + z1 + 2.f * t3 - y2[t] + cb[c];
        float vs = vnr[0] * vw[c]        + vb[c]
                 + vnr[1] * vw[OUTC + c] + vb[OUTC + c]
                 + vnr[2] * vw[2*OUTC+c] + vb[2*OUTC+c];
        ev = tanhf(u) + vs;
        e[t] = ev;
    }
    __syncthreads();

    if (head == 0) {
        if (t < NNODES) {                      // logits: thread t owns out[t]
            float s = (c == 0) ? afcb[t] : 0.f;
            const float* wrow = afw + (size_t)c * 100 + t;   // row f=n*60+c
#pragma unroll 4
            for (int n = 0; n < NNODES; ++n) s += e[n] * wrow[(size_t)n * 6000];
            atomicAdd(&out[t], s);
        }
    } else {
        // critic: wave-shuffle reduction of e[t]*cfw[t*60+c] (no LDS atomics)
        float p = (t < NNODES) ? ev * cfw[t * OUTC + c] : 0.f;
#pragma unroll
        for (int off = 32; off > 0; off >>= 1) p += __shfl_down(p, off, 64);
        __shared__ float wsum[2];
        if ((t & 63) == 0) wsum[t >> 6] = p;
        __syncthreads();
        if (t == 0) atomicAdd(&out[100], wsum[0] + wsum[1] + (c == 0 ? cfcb[0] : 0.f));
    }
}

// ---------------- launch ----------------
extern "C" void kernel_launch(void* const* d_in, const int* in_sizes, int n_in,
                              void* d_out, int out_size, void* d_ws, size_t ws_size,
                              hipStream_t stream) {
    const float* x    = (const float*)d_in[0];
    const int*   ei   = (const int*)  d_in[1];
    const float* vnr  = (const float*)d_in[2];
    const float* wa   = (const float*)d_in[3];
    const float* acb  = (const float*)d_in[4];
    const float* wc   = (const float*)d_in[5];
    const float* ccb  = (const float*)d_in[6];
    const float* avw  = (const float*)d_in[7];
    const float* avb  = (const float*)d_in[8];
    const float* cvw  = (const float*)d_in[9];
    const float* cvb  = (const float*)d_in[10];
    const float* afw  = (const float*)d_in[11];
    const float* afcb = (const float*)d_in[12];
    const float* cfw  = (const float*)d_in[13];
    const float* cfcb = (const float*)d_in[14];

    float* ws = (float*)d_ws;
    float* Y  = ws + WS_Y;
    float* out = (float*)d_out;

    if (ws_size >= WS_NEED_BYTES) {
        unsigned short* xb = (unsigned short*)((char*)d_ws + XB_OFF_BYTES);
        k_cvt_x<<<800, 256, 0, stream>>>(x, (ushort8*)xb, Y, out); // zeroes Y+out
        k_gemm11<<<384, 256, 0, stream>>>(xb, wa, wc, Y);
    } else {
        hipError_t e1 = hipMemsetAsync((char*)d_ws + WS_Y * 4, 0,
                                       (WS_E - WS_Y) * 4, stream);
        hipError_t e2 = hipMemsetAsync(d_out, 0, 101 * sizeof(float), stream);
        (void)e1; (void)e2;
        k_gemm_f32<<<dim3(6, NKC), 256, 0, stream>>>(x, wa, wc, Y);
    }

    k_embh<<<120, 128, 0, stream>>>(ei, Y, vnr, avw, avb, cvw, cvb,
                                    acb, ccb, afcb, cfcb, afw, cfw, out);
}